// Round 7
// baseline (345.714 us; speedup 1.0000x reference)
//
#include <hip/hip_runtime.h>
#include <math.h>

// Problem constants
#define B_N   4
#define CIN   21
#define HIDC  48
#define H0    81
#define NP    6561      // 81*81
#define HH    324
#define NPH   104976    // 324*324

__device__ __forceinline__ float tanh_fast(float x) {
    float e = __expf(2.f * x);
    return 1.f - 2.f / (e + 1.f);
}

// ---------------------------------------------------------------------------
// K1 v7: conv1 both heads (21 -> 96), relu. NO LDS: weight indices are
// wave-uniform (blockIdx.y group + unrolled loop constants) so they compile
// to s_load through the scalar/constant cache, overlapping the VALU FMA
// stream. x reads are coalesced per-lane loads with hoisted clamped offsets
// + {0,1} masks (bounds logic computed once, not per ic).
// ---------------------------------------------------------------------------
__global__ __launch_bounds__(256) void k1_conv1(
    const float* __restrict__ x,
    const float* __restrict__ w1o, const float* __restrict__ b1o,
    const float* __restrict__ w1g, const float* __restrict__ b1g,
    float* __restrict__ hid_o, float* __restrict__ hid_g)
{
    const int tid = threadIdx.x;
    const int grp = blockIdx.y;          // 0..7 ; 0..3 -> head_o, 4..7 -> head_g
    const int b   = blockIdx.z;
    const bool head_o = (grp < 4);
    const int ocb = (grp & 3) * 12;      // oc base within the head
    const float* __restrict__ wsrc = head_o ? w1o : w1g;
    const float* __restrict__ bsrc = head_o ? b1o : b1g;

    const int px = blockIdx.x * 256 + tid;
    const bool valid = (px < NP);
    const int oy = px / H0, ox = px - oy * H0;
    const float* xb = x + (size_t)b * CIN * NP;

    // hoisted neighbor offsets + masks
    int off[9];
    float msk[9];
    #pragma unroll
    for (int t = 0; t < 9; t++) {
        const int dy = t / 3 - 1, dx = t % 3 - 1;
        const int iy = oy + dy, ix = ox + dx;
        const bool ok = valid && ((unsigned)iy < (unsigned)H0) && ((unsigned)ix < (unsigned)H0);
        off[t] = ok ? iy * H0 + ix : 0;
        msk[t] = ok ? 1.f : 0.f;
    }

    float acc[12];
    #pragma unroll
    for (int j = 0; j < 12; j++) acc[j] = bsrc[ocb + j];   // uniform -> s_load

    for (int ic = 0; ic < CIN; ic++) {
        const float* xc = xb + ic * NP;
        float xv[9];
        #pragma unroll
        for (int t = 0; t < 9; t++) xv[t] = xc[off[t]] * msk[t];
        #pragma unroll
        for (int tap = 0; tap < 9; tap++) {
            const int wi = ic * 9 + tap;                   // uniform
            #pragma unroll
            for (int j = 0; j < 12; j++)
                acc[j] = fmaf(xv[tap], wsrc[(ocb + j) * 189 + wi], acc[j]);
        }
    }

    if (valid) {
        float* outp = (head_o ? hid_o : hid_g) + ((size_t)b * HIDC + ocb) * NP + px;
        #pragma unroll
        for (int j = 0; j < 12; j++) outp[j * NP] = fmaxf(acc[j], 0.f);
    }
}

// ---------------------------------------------------------------------------
// K2 v5: conv2 both heads + mask epilogue. Slice = WAVE id (block 512 =
// 8 waves x 64 px), so weight indices are wave-uniform -> s_load (no LDS
// for weights). Each wave reduces 6 input channels; cross-wave reduction
// via LDS; epilogue on wave 0 (64 px); coalesced 27-plane stores.
// ---------------------------------------------------------------------------
__global__ __launch_bounds__(512) void k2_conv2_masks(
    const float* __restrict__ hid_o, const float* __restrict__ hid_g,
    const float* __restrict__ w2o, const float* __restrict__ b2o,
    const float* __restrict__ w2g, const float* __restrict__ b2g,
    float* __restrict__ v_out,
    float* __restrict__ g_buf, float* __restrict__ m_lp, float* __restrict__ m_hp)
{
    __shared__ float red[8][64][10];     // [wave/slice][px][9 partials]
    __shared__ float res_s[64][28];      // 27 outputs per px
    const int tid  = threadIdx.x;
    const int lane = tid & 63;
    const int s    = tid >> 6;           // wave id == channel slice (uniform!)
    const int b    = blockIdx.y;
    const int px0  = blockIdx.x * 64;
    const int px   = px0 + lane;
    const bool valid = (px < NP);
    const int oy = px / H0, ox = px - oy * H0;
    const int ic0 = s * 6;
    const float* po = hid_o + ((size_t)b * HIDC + ic0) * NP;
    const float* pg = hid_g + ((size_t)b * HIDC + ic0) * NP;

    float a[8] = {0.f, 0.f, 0.f, 0.f, 0.f, 0.f, 0.f, 0.f};
    float ag = 0.f;

    #pragma unroll
    for (int ky = 0; ky < 3; ky++) {
        const int iy = oy + ky - 1;
        const bool rok = valid && ((unsigned)iy < (unsigned)H0);
        #pragma unroll
        for (int kx = 0; kx < 3; kx++) {
            const int ix = ox + kx - 1;
            const bool ok = rok && ((unsigned)ix < (unsigned)H0);
            const int offp = iy * H0 + ix;
            const int tap = ky * 3 + kx;
            #pragma unroll
            for (int j = 0; j < 6; j++) {
                const float vo = ok ? po[j * NP + offp] : 0.f;
                const float vg = ok ? pg[j * NP + offp] : 0.f;
                const int wi = (ic0 + j) * 9 + tap;        // wave-uniform
                #pragma unroll
                for (int d = 0; d < 8; d++)
                    a[d] = fmaf(vo, w2o[d * (HIDC * 9) + wi], a[d]);
                ag = fmaf(vg, w2g[wi], ag);
            }
        }
    }

    #pragma unroll
    for (int n = 0; n < 8; n++) red[s][lane][n] = a[n];
    red[s][lane][8] = ag;
    __syncthreads();

    if (tid < 64 && valid) {
        float v[8];
        #pragma unroll
        for (int n = 0; n < 8; n++) {
            float t = 0.f;
            #pragma unroll
            for (int w = 0; w < 8; w++) t += red[w][tid][n];
            v[n] = tanh_fast(t + b2o[n]);
        }
        float agf = b2g[0];
        #pragma unroll
        for (int w = 0; w < 8; w++) agf += red[w][tid][8];
        const float g = 1.f / (1.f + __expf(-agf));

        constexpr float DT[8][9] = {
            {-1, 0, 1, -1, 0, 1, -1, 0, 1},
            {-1,-1, 0, -1, 0, 1,  0, 1, 1},
            {-1,-1,-1,  0, 0, 0,  1, 1, 1},
            { 0,-1,-1,  1, 0,-1,  1, 1, 0},
            { 1, 0,-1,  1, 0,-1,  1, 0,-1},
            { 1, 1, 0,  1, 0,-1,  0,-1,-1},
            { 1, 1, 1,  0, 0, 0, -1,-1,-1},
            { 0, 1, 1, -1, 0, 1, -1,-1, 0}};
        float ker[9];
        #pragma unroll
        for (int n = 0; n < 9; n++) {
            float t = 0.f;
            #pragma unroll
            for (int d = 0; d < 8; d++) t += v[d] * DT[d][n];
            ker[n] = -0.125f * t;
        }
        ker[4] += 2.5f;
        float mx = ker[0];
        #pragma unroll
        for (int n = 1; n < 9; n++) mx = fmaxf(mx, ker[n]);
        float exn[9], sum = 0.f;
        #pragma unroll
        for (int n = 0; n < 9; n++) { exn[n] = __expf((ker[n] - mx) * 2.0f); sum += exn[n]; }
        const float rs = 1.f / sum;
        float mean = 0.f;
        #pragma unroll
        for (int n = 0; n < 9; n++) mean += ker[n];
        mean *= (1.f / 9.f);
        float den = 1e-8f;
        #pragma unroll
        for (int n = 0; n < 9; n++) den += fabsf(ker[n] - mean);
        const float rd = 1.f / den;

        #pragma unroll
        for (int n = 0; n < 8; n++) res_s[tid][n] = v[n];
        res_s[tid][8] = g;
        #pragma unroll
        for (int n = 0; n < 9; n++) {
            res_s[tid][9 + n]  = exn[n] * rs;
            res_s[tid][18 + n] = (ker[n] - mean) * rd;
        }
    }
    __syncthreads();

    for (int j = tid; j < 27 * 64; j += 512) {
        const int plane = j >> 6, pl = j & 63;
        const int p = px0 + pl;
        if (p >= NP) continue;
        const float val = res_s[pl][plane];
        float* dst;
        if (plane < 8)        dst = v_out + ((size_t)b * 8 + plane) * NP;
        else if (plane == 8)  dst = g_buf + (size_t)b * NP;
        else if (plane < 18)  dst = m_lp + ((size_t)b * 9 + (plane - 9)) * NP;
        else                  dst = m_hp + ((size_t)b * 9 + (plane - 18)) * NP;
        dst[p] = val;
    }
}

// ---------------------------------------------------------------------------
// K4 v3 (unchanged): hi-res blend, low-res-row-centric.
// ---------------------------------------------------------------------------
__global__ __launch_bounds__(256) void k4_up(
    const float* __restrict__ x, const float* __restrict__ g_buf,
    const float* __restrict__ m_lp, const float* __restrict__ m_hp,
    const float* __restrict__ beta,
    float* __restrict__ y_out, float* __restrict__ gup_out)
{
    __shared__ float ml_s[9][81];
    __shared__ float mh_s[9][81];
    __shared__ float g_s[81];
    __shared__ float xrow[3][11][84];
    __shared__ float alp_s[11][84];
    __shared__ float ahp_s[11][84];
    const int tid  = threadIdx.x;
    const int h0r  = blockIdx.x;         // 0..80
    const int ygrp = blockIdx.y;         // 0..1
    const int b    = blockIdx.z;
    const int c0   = ygrp * 11;
    const int nc   = (ygrp == 0) ? 11 : 10;

    const int rb = h0r * H0;
    for (int i = tid; i < 19 * 81; i += 256) {
        const int pl = i / 81, wq = i - pl * 81;
        if (pl < 9)       ml_s[pl][wq] = m_lp[((size_t)b * 9 + pl) * NP + rb + wq];
        else if (pl < 18) mh_s[pl - 9][wq] = m_hp[((size_t)b * 9 + (pl - 9)) * NP + rb + wq];
        else              g_s[wq] = g_buf[(size_t)b * NP + rb + wq];
    }
    const int r0 = (h0r == 0) ? 1 : h0r - 1;
    const int r2 = (h0r == H0 - 1) ? H0 - 2 : h0r + 1;
    const int rr[3] = {r0, h0r, r2};
    for (int i = tid; i < 3 * nc * 81; i += 256) {
        const int t = i / (nc * 81), rem = i - t * nc * 81;
        const int cc = rem / 81, wq = rem - cc * 81;
        xrow[t][cc][wq] = x[((size_t)b * CIN + c0 + cc) * NP + rr[t] * H0 + wq];
    }
    __syncthreads();

    for (int i = tid; i < nc * 81; i += 256) {
        const int cc = i / 81, wq = i - cc * 81;
        const int xm = (wq == 0) ? 1 : wq - 1;
        const int xp = (wq == H0 - 1) ? H0 - 2 : wq + 1;
        float alp = 0.f, ahp = 0.f;
        #pragma unroll
        for (int t = 0; t < 3; t++) {
            const float p0 = xrow[t][cc][xm];
            const float p1 = xrow[t][cc][wq];
            const float p2 = xrow[t][cc][xp];
            alp += p0 * ml_s[t * 3 + 0][wq] + p1 * ml_s[t * 3 + 1][wq] + p2 * ml_s[t * 3 + 2][wq];
            ahp += p0 * mh_s[t * 3 + 0][wq] + p1 * mh_s[t * 3 + 1][wq] + p2 * mh_s[t * 3 + 2][wq];
        }
        alp_s[cc][wq] = alp;
        ahp_s[cc][wq] = ahp;
    }
    __syncthreads();

    const float tb = tanh_fast(beta[0]);
    for (int i = tid; i < 11 * 4 * 81; i += 256) {
        const int pl = i / 324, rem = i - pl * 324;
        const int dh = rem / 81, wq = rem - dh * 81;
        const int H = h0r * 4 + dh;
        if (ygrp == 1 && pl == 10) {
            const float g = g_s[wq];
            *reinterpret_cast<float4*>(gup_out + (size_t)b * NPH + H * HH + wq * 4) =
                make_float4(g, g, g, g);
            continue;
        }
        const int cc = pl;
        const int c = c0 + pl;
        const float g = g_s[wq];
        const float lam = 0.15f * (1.f - g);
        const float gh = tb * g;
        const float alp = alp_s[cc][wq];
        const float ahp = ahp_s[cc][wq];
        const float ysf = (float)H * (80.f / 323.f);
        int y0 = (int)ysf;
        if (y0 > H0 - 2) y0 = H0 - 2;
        const float wy = ysf - (float)y0;
        const int sy = y0 - h0r + 1;
        const int xm = (wq == 0) ? 1 : wq - 1;
        const int xp = (wq == H0 - 1) ? H0 - 2 : wq + 1;
        const float a0 = xrow[sy][cc][(wq == 0) ? 0 : xm];
        const float a1 = xrow[sy][cc][wq];
        const float a2 = xrow[sy][cc][(wq == H0 - 1) ? H0 - 1 : xp];
        const float b0 = xrow[sy + 1][cc][(wq == 0) ? 0 : xm];
        const float b1 = xrow[sy + 1][cc][wq];
        const float b2 = xrow[sy + 1][cc][(wq == H0 - 1) ? H0 - 1 : xp];
        float res[4];
        #pragma unroll
        for (int k = 0; k < 4; k++) {
            const int W = wq * 4 + k;
            const float xsf = (float)W * (80.f / 323.f);
            int x0 = (int)xsf;
            if (x0 > H0 - 2) x0 = H0 - 2;
            const float wx = xsf - (float)x0;
            const int sx = x0 - wq + 1;
            const float top = (sx == 0) ? a0 + (a1 - a0) * wx : a1 + (a2 - a1) * wx;
            const float bot = (sx == 0) ? b0 + (b1 - b0) * wx : b1 + (b2 - b1) * wx;
            const float xup = top + (bot - top) * wy;
            res[k] = xup + lam * (alp - xup) + gh * ahp;
        }
        *reinterpret_cast<float4*>(y_out + ((size_t)b * CIN + c) * NPH + H * HH + wq * 4) =
            make_float4(res[0], res[1], res[2], res[3]);
    }
}

// ---------------------------------------------------------------------------
extern "C" void kernel_launch(void* const* d_in, const int* in_sizes, int n_in,
                              void* d_out, int out_size, void* d_ws, size_t ws_size,
                              hipStream_t stream)
{
    const float* x    = (const float*)d_in[0];
    const float* w1o  = (const float*)d_in[1];
    const float* b1o  = (const float*)d_in[2];
    const float* w2o  = (const float*)d_in[3];
    const float* b2o  = (const float*)d_in[4];
    const float* w1g  = (const float*)d_in[5];
    const float* b1g  = (const float*)d_in[6];
    const float* w2g  = (const float*)d_in[7];
    const float* b2g  = (const float*)d_in[8];
    const float* beta = (const float*)d_in[9];
    float* out = (float*)d_out;
    float* wsf = (float*)d_ws;

    float* hid_o = wsf;
    float* hid_g = hid_o + (size_t)B_N * HIDC * NP;
    float* m_lp  = hid_g + (size_t)B_N * HIDC * NP;
    float* m_hp  = m_lp + (size_t)B_N * 9 * NP;
    float* g_buf = m_hp + (size_t)B_N * 9 * NP;

    // output layout: y [4,21,324,324], v [4,8,81,81], g_up [4,1,324,324]
    float* y_out = out;
    float* v_out = out + (size_t)B_N * CIN * NPH;
    float* gup   = v_out + (size_t)B_N * 8 * NP;

    k1_conv1<<<dim3((NP + 255) / 256, 8, B_N), 256, 0, stream>>>(
        x, w1o, b1o, w1g, b1g, hid_o, hid_g);
    k2_conv2_masks<<<dim3((NP + 63) / 64, B_N), 512, 0, stream>>>(
        hid_o, hid_g, w2o, b2o, w2g, b2g, v_out, g_buf, m_lp, m_hp);
    k4_up<<<dim3(H0, 2, B_N), 256, 0, stream>>>(x, g_buf, m_lp, m_hp, beta, y_out, gup);
}

// Round 8
// 159.187 us; speedup vs baseline: 2.1717x; 2.1717x over previous
//
#include <hip/hip_runtime.h>
#include <math.h>

// Problem constants
#define B_N   4
#define CIN   21
#define HIDC  48
#define H0    81
#define NP    6561      // 81*81
#define HH    324
#define NPH   104976    // 324*324

__device__ __forceinline__ float tanh_fast(float x) {
    float e = __expf(2.f * x);
    return 1.f - 2.f / (e + 1.f);
}

// ---------------------------------------------------------------------------
// K1 v7 (keep): conv1 both heads (21 -> 96), relu. NO LDS: weight indices
// derive only from blockIdx + unrolled constants -> provably wave-uniform ->
// s_load through the scalar cache (bypasses the per-CU LDS pipe that capped
// v4/v5/v6 at ~35-50 us). x reads coalesced with hoisted offsets + masks.
// ---------------------------------------------------------------------------
__global__ __launch_bounds__(256) void k1_conv1(
    const float* __restrict__ x,
    const float* __restrict__ w1o, const float* __restrict__ b1o,
    const float* __restrict__ w1g, const float* __restrict__ b1g,
    float* __restrict__ hid_o, float* __restrict__ hid_g)
{
    const int tid = threadIdx.x;
    const int grp = blockIdx.y;          // 0..7 ; 0..3 -> head_o, 4..7 -> head_g
    const int b   = blockIdx.z;
    const bool head_o = (grp < 4);
    const int ocb = (grp & 3) * 12;
    const float* __restrict__ wsrc = head_o ? w1o : w1g;
    const float* __restrict__ bsrc = head_o ? b1o : b1g;

    const int px = blockIdx.x * 256 + tid;
    const bool valid = (px < NP);
    const int oy = px / H0, ox = px - oy * H0;
    const float* xb = x + (size_t)b * CIN * NP;

    int off[9];
    float msk[9];
    #pragma unroll
    for (int t = 0; t < 9; t++) {
        const int dy = t / 3 - 1, dx = t % 3 - 1;
        const int iy = oy + dy, ix = ox + dx;
        const bool ok = valid && ((unsigned)iy < (unsigned)H0) && ((unsigned)ix < (unsigned)H0);
        off[t] = ok ? iy * H0 + ix : 0;
        msk[t] = ok ? 1.f : 0.f;
    }

    float acc[12];
    #pragma unroll
    for (int j = 0; j < 12; j++) acc[j] = bsrc[ocb + j];   // uniform -> s_load

    for (int ic = 0; ic < CIN; ic++) {
        const float* xc = xb + ic * NP;
        float xv[9];
        #pragma unroll
        for (int t = 0; t < 9; t++) xv[t] = xc[off[t]] * msk[t];
        #pragma unroll
        for (int tap = 0; tap < 9; tap++) {
            const int wi = ic * 9 + tap;                   // uniform
            #pragma unroll
            for (int j = 0; j < 12; j++)
                acc[j] = fmaf(xv[tap], wsrc[(ocb + j) * 189 + wi], acc[j]);
        }
    }

    if (valid) {
        float* outp = (head_o ? hid_o : hid_g) + ((size_t)b * HIDC + ocb) * NP + px;
        #pragma unroll
        for (int j = 0; j < 12; j++) outp[j * NP] = fmaxf(acc[j], 0.f);
    }
}

// ---------------------------------------------------------------------------
// K2 v6: revert to the proven v4 structure (LDS weights, slice = tid>>5,
// shfl+LDS reduce) but each thread now computes TWO pixels (p0, p0+32) with
// the SAME weight registers -> LDS b128 instructions per pixel halve (the
// per-CU LDS pipe was v4's dominant cost). Block covers 64 px.
// ---------------------------------------------------------------------------
__global__ __launch_bounds__(256) void k2_conv2_masks(
    const float* __restrict__ hid_o, const float* __restrict__ hid_g,
    const float* __restrict__ w2o, const float* __restrict__ b2o,
    const float* __restrict__ w2g, const float* __restrict__ b2g,
    float* __restrict__ v_out,
    float* __restrict__ g_buf, float* __restrict__ m_lp, float* __restrict__ m_hp)
{
    __shared__ __align__(16) float wo_s[HIDC * 9 * 8];  // [(ic*9+tap)*8 + d]
    __shared__ float wg_s[HIDC * 9];
    __shared__ float red[4][64][12];                    // [wave][px64][9 partials]
    __shared__ float res_s[64][28];
    const int tid = threadIdx.x;
    const int b = blockIdx.y;

    for (int i = tid; i < HIDC * 9 * 8; i += 256) {
        const int d = i / (HIDC * 9), r = i - d * (HIDC * 9);
        wo_s[r * 8 + d] = w2o[i];
    }
    for (int i = tid; i < HIDC * 9; i += 256) wg_s[i] = w2g[i];
    __syncthreads();

    const int pxl = tid & 31;
    const int s   = tid >> 5;                // slice 0..7 (6 ic each)
    const int w   = tid >> 6;                // wave
    const int px0b = blockIdx.x * 64;
    const int p0  = px0b + pxl;
    const int p1  = p0 + 32;
    const bool v0 = (p0 < NP), v1 = (p1 < NP);
    const int oy0 = p0 / H0, ox0 = p0 - oy0 * H0;
    const int oy1 = p1 / H0, ox1 = p1 - oy1 * H0;
    const int ic0 = s * 6;
    const float* po = hid_o + ((size_t)b * HIDC + ic0) * NP;
    const float* pg = hid_g + ((size_t)b * HIDC + ic0) * NP;

    float a0[8] = {0,0,0,0,0,0,0,0}, a1[8] = {0,0,0,0,0,0,0,0};
    float ag0 = 0.f, ag1 = 0.f;

    #pragma unroll 1
    for (int ky = 0; ky < 3; ky++) {
        const int iy0 = oy0 + ky - 1, iy1 = oy1 + ky - 1;
        const bool r0k = v0 && ((unsigned)iy0 < (unsigned)H0);
        const bool r1k = v1 && ((unsigned)iy1 < (unsigned)H0);
        #pragma unroll
        for (int kx = 0; kx < 3; kx++) {
            const int ix0 = ox0 + kx - 1, ix1 = ox1 + kx - 1;
            const bool ok0 = r0k && ((unsigned)ix0 < (unsigned)H0);
            const bool ok1 = r1k && ((unsigned)ix1 < (unsigned)H0);
            const int of0 = iy0 * H0 + ix0, of1 = iy1 * H0 + ix1;
            const int tap = ky * 3 + kx;
            #pragma unroll
            for (int j = 0; j < 6; j++) {
                const float vo0 = ok0 ? po[j * NP + of0] : 0.f;
                const float vo1 = ok1 ? po[j * NP + of1] : 0.f;
                const float vg0 = ok0 ? pg[j * NP + of0] : 0.f;
                const float vg1 = ok1 ? pg[j * NP + of1] : 0.f;
                const int wb = ((ic0 + j) * 9 + tap) * 8;
                const float4 wA = *(const float4*)&wo_s[wb];
                const float4 wB = *(const float4*)&wo_s[wb + 4];
                a0[0] = fmaf(vo0, wA.x, a0[0]); a1[0] = fmaf(vo1, wA.x, a1[0]);
                a0[1] = fmaf(vo0, wA.y, a0[1]); a1[1] = fmaf(vo1, wA.y, a1[1]);
                a0[2] = fmaf(vo0, wA.z, a0[2]); a1[2] = fmaf(vo1, wA.z, a1[2]);
                a0[3] = fmaf(vo0, wA.w, a0[3]); a1[3] = fmaf(vo1, wA.w, a1[3]);
                a0[4] = fmaf(vo0, wB.x, a0[4]); a1[4] = fmaf(vo1, wB.x, a1[4]);
                a0[5] = fmaf(vo0, wB.y, a0[5]); a1[5] = fmaf(vo1, wB.y, a1[5]);
                a0[6] = fmaf(vo0, wB.z, a0[6]); a1[6] = fmaf(vo1, wB.z, a1[6]);
                a0[7] = fmaf(vo0, wB.w, a0[7]); a1[7] = fmaf(vo1, wB.w, a1[7]);
                const float wgv = wg_s[(ic0 + j) * 9 + tap];
                ag0 = fmaf(vg0, wgv, ag0);
                ag1 = fmaf(vg1, wgv, ag1);
            }
        }
    }

    // sum the wave's two slices (lane^32 = same px, other slice)
    #pragma unroll
    for (int n = 0; n < 8; n++) {
        a0[n] += __shfl_xor(a0[n], 32);
        a1[n] += __shfl_xor(a1[n], 32);
    }
    ag0 += __shfl_xor(ag0, 32);
    ag1 += __shfl_xor(ag1, 32);
    if ((tid & 32) == 0) {
        #pragma unroll
        for (int n = 0; n < 8; n++) {
            red[w][pxl][n]      = a0[n];
            red[w][pxl + 32][n] = a1[n];
        }
        red[w][pxl][8]      = ag0;
        red[w][pxl + 32][8] = ag1;
    }
    __syncthreads();

    if (tid < 64 && (px0b + tid) < NP) {
        float v[8];
        #pragma unroll
        for (int n = 0; n < 8; n++)
            v[n] = tanh_fast(red[0][tid][n] + red[1][tid][n] + red[2][tid][n]
                             + red[3][tid][n] + b2o[n]);
        const float agf = red[0][tid][8] + red[1][tid][8] + red[2][tid][8]
                        + red[3][tid][8] + b2g[0];
        const float g = 1.f / (1.f + __expf(-agf));

        constexpr float DT[8][9] = {
            {-1, 0, 1, -1, 0, 1, -1, 0, 1},
            {-1,-1, 0, -1, 0, 1,  0, 1, 1},
            {-1,-1,-1,  0, 0, 0,  1, 1, 1},
            { 0,-1,-1,  1, 0,-1,  1, 1, 0},
            { 1, 0,-1,  1, 0,-1,  1, 0,-1},
            { 1, 1, 0,  1, 0,-1,  0,-1,-1},
            { 1, 1, 1,  0, 0, 0, -1,-1,-1},
            { 0, 1, 1, -1, 0, 1, -1,-1, 0}};
        float ker[9];
        #pragma unroll
        for (int n = 0; n < 9; n++) {
            float t = 0.f;
            #pragma unroll
            for (int d = 0; d < 8; d++) t += v[d] * DT[d][n];
            ker[n] = -0.125f * t;
        }
        ker[4] += 2.5f;
        float mx = ker[0];
        #pragma unroll
        for (int n = 1; n < 9; n++) mx = fmaxf(mx, ker[n]);
        float exn[9], sum = 0.f;
        #pragma unroll
        for (int n = 0; n < 9; n++) { exn[n] = __expf((ker[n] - mx) * 2.0f); sum += exn[n]; }
        const float rs = 1.f / sum;
        float mean = 0.f;
        #pragma unroll
        for (int n = 0; n < 9; n++) mean += ker[n];
        mean *= (1.f / 9.f);
        float den = 1e-8f;
        #pragma unroll
        for (int n = 0; n < 9; n++) den += fabsf(ker[n] - mean);
        const float rd = 1.f / den;

        #pragma unroll
        for (int n = 0; n < 8; n++) res_s[tid][n] = v[n];
        res_s[tid][8] = g;
        #pragma unroll
        for (int n = 0; n < 9; n++) {
            res_s[tid][9 + n]  = exn[n] * rs;
            res_s[tid][18 + n] = (ker[n] - mean) * rd;
        }
    }
    __syncthreads();

    for (int j = tid; j < 27 * 64; j += 256) {
        const int plane = j >> 6, pl = j & 63;
        const int p = px0b + pl;
        if (p >= NP) continue;
        const float val = res_s[pl][plane];
        float* dst;
        if (plane < 8)        dst = v_out + ((size_t)b * 8 + plane) * NP;
        else if (plane == 8)  dst = g_buf + (size_t)b * NP;
        else if (plane < 18)  dst = m_lp + ((size_t)b * 9 + (plane - 9)) * NP;
        else                  dst = m_hp + ((size_t)b * 9 + (plane - 18)) * NP;
        dst[p] = val;
    }
}

// ---------------------------------------------------------------------------
// K4 v3 (keep): hi-res blend, low-res-row-centric.
// ---------------------------------------------------------------------------
__global__ __launch_bounds__(256) void k4_up(
    const float* __restrict__ x, const float* __restrict__ g_buf,
    const float* __restrict__ m_lp, const float* __restrict__ m_hp,
    const float* __restrict__ beta,
    float* __restrict__ y_out, float* __restrict__ gup_out)
{
    __shared__ float ml_s[9][81];
    __shared__ float mh_s[9][81];
    __shared__ float g_s[81];
    __shared__ float xrow[3][11][84];
    __shared__ float alp_s[11][84];
    __shared__ float ahp_s[11][84];
    const int tid  = threadIdx.x;
    const int h0r  = blockIdx.x;         // 0..80
    const int ygrp = blockIdx.y;         // 0..1
    const int b    = blockIdx.z;
    const int c0   = ygrp * 11;
    const int nc   = (ygrp == 0) ? 11 : 10;

    const int rb = h0r * H0;
    for (int i = tid; i < 19 * 81; i += 256) {
        const int pl = i / 81, wq = i - pl * 81;
        if (pl < 9)       ml_s[pl][wq] = m_lp[((size_t)b * 9 + pl) * NP + rb + wq];
        else if (pl < 18) mh_s[pl - 9][wq] = m_hp[((size_t)b * 9 + (pl - 9)) * NP + rb + wq];
        else              g_s[wq] = g_buf[(size_t)b * NP + rb + wq];
    }
    const int r0 = (h0r == 0) ? 1 : h0r - 1;
    const int r2 = (h0r == H0 - 1) ? H0 - 2 : h0r + 1;
    const int rr[3] = {r0, h0r, r2};
    for (int i = tid; i < 3 * nc * 81; i += 256) {
        const int t = i / (nc * 81), rem = i - t * nc * 81;
        const int cc = rem / 81, wq = rem - cc * 81;
        xrow[t][cc][wq] = x[((size_t)b * CIN + c0 + cc) * NP + rr[t] * H0 + wq];
    }
    __syncthreads();

    for (int i = tid; i < nc * 81; i += 256) {
        const int cc = i / 81, wq = i - cc * 81;
        const int xm = (wq == 0) ? 1 : wq - 1;
        const int xp = (wq == H0 - 1) ? H0 - 2 : wq + 1;
        float alp = 0.f, ahp = 0.f;
        #pragma unroll
        for (int t = 0; t < 3; t++) {
            const float p0 = xrow[t][cc][xm];
            const float p1 = xrow[t][cc][wq];
            const float p2 = xrow[t][cc][xp];
            alp += p0 * ml_s[t * 3 + 0][wq] + p1 * ml_s[t * 3 + 1][wq] + p2 * ml_s[t * 3 + 2][wq];
            ahp += p0 * mh_s[t * 3 + 0][wq] + p1 * mh_s[t * 3 + 1][wq] + p2 * mh_s[t * 3 + 2][wq];
        }
        alp_s[cc][wq] = alp;
        ahp_s[cc][wq] = ahp;
    }
    __syncthreads();

    const float tb = tanh_fast(beta[0]);
    for (int i = tid; i < 11 * 4 * 81; i += 256) {
        const int pl = i / 324, rem = i - pl * 324;
        const int dh = rem / 81, wq = rem - dh * 81;
        const int H = h0r * 4 + dh;
        if (ygrp == 1 && pl == 10) {
            const float g = g_s[wq];
            *reinterpret_cast<float4*>(gup_out + (size_t)b * NPH + H * HH + wq * 4) =
                make_float4(g, g, g, g);
            continue;
        }
        const int cc = pl;
        const int c = c0 + pl;
        const float g = g_s[wq];
        const float lam = 0.15f * (1.f - g);
        const float gh = tb * g;
        const float alp = alp_s[cc][wq];
        const float ahp = ahp_s[cc][wq];
        const float ysf = (float)H * (80.f / 323.f);
        int y0 = (int)ysf;
        if (y0 > H0 - 2) y0 = H0 - 2;
        const float wy = ysf - (float)y0;
        const int sy = y0 - h0r + 1;
        const int xm = (wq == 0) ? 1 : wq - 1;
        const int xp = (wq == H0 - 1) ? H0 - 2 : wq + 1;
        const float a0 = xrow[sy][cc][(wq == 0) ? 0 : xm];
        const float a1 = xrow[sy][cc][wq];
        const float a2 = xrow[sy][cc][(wq == H0 - 1) ? H0 - 1 : xp];
        const float b0 = xrow[sy + 1][cc][(wq == 0) ? 0 : xm];
        const float b1 = xrow[sy + 1][cc][wq];
        const float b2 = xrow[sy + 1][cc][(wq == H0 - 1) ? H0 - 1 : xp];
        float res[4];
        #pragma unroll
        for (int k = 0; k < 4; k++) {
            const int W = wq * 4 + k;
            const float xsf = (float)W * (80.f / 323.f);
            int x0 = (int)xsf;
            if (x0 > H0 - 2) x0 = H0 - 2;
            const float wx = xsf - (float)x0;
            const int sx = x0 - wq + 1;
            const float top = (sx == 0) ? a0 + (a1 - a0) * wx : a1 + (a2 - a1) * wx;
            const float bot = (sx == 0) ? b0 + (b1 - b0) * wx : b1 + (b2 - b1) * wx;
            const float xup = top + (bot - top) * wy;
            res[k] = xup + lam * (alp - xup) + gh * ahp;
        }
        *reinterpret_cast<float4*>(y_out + ((size_t)b * CIN + c) * NPH + H * HH + wq * 4) =
            make_float4(res[0], res[1], res[2], res[3]);
    }
}

// ---------------------------------------------------------------------------
extern "C" void kernel_launch(void* const* d_in, const int* in_sizes, int n_in,
                              void* d_out, int out_size, void* d_ws, size_t ws_size,
                              hipStream_t stream)
{
    const float* x    = (const float*)d_in[0];
    const float* w1o  = (const float*)d_in[1];
    const float* b1o  = (const float*)d_in[2];
    const float* w2o  = (const float*)d_in[3];
    const float* b2o  = (const float*)d_in[4];
    const float* w1g  = (const float*)d_in[5];
    const float* b1g  = (const float*)d_in[6];
    const float* w2g  = (const float*)d_in[7];
    const float* b2g  = (const float*)d_in[8];
    const float* beta = (const float*)d_in[9];
    float* out = (float*)d_out;
    float* wsf = (float*)d_ws;

    float* hid_o = wsf;
    float* hid_g = hid_o + (size_t)B_N * HIDC * NP;
    float* m_lp  = hid_g + (size_t)B_N * HIDC * NP;
    float* m_hp  = m_lp + (size_t)B_N * 9 * NP;
    float* g_buf = m_hp + (size_t)B_N * 9 * NP;

    // output layout: y [4,21,324,324], v [4,8,81,81], g_up [4,1,324,324]
    float* y_out = out;
    float* v_out = out + (size_t)B_N * CIN * NPH;
    float* gup   = v_out + (size_t)B_N * 8 * NP;

    k1_conv1<<<dim3((NP + 255) / 256, 8, B_N), 256, 0, stream>>>(
        x, w1o, b1o, w1g, b1g, hid_o, hid_g);
    k2_conv2_masks<<<dim3((NP + 63) / 64, B_N), 256, 0, stream>>>(
        hid_o, hid_g, w2o, b2o, w2g, b2g, v_out, g_buf, m_lp, m_hp);
    k4_up<<<dim3(H0, 2, B_N), 256, 0, stream>>>(x, g_buf, m_lp, m_hp, beta, y_out, gup);
}